// Round 1
// 329.874 us; speedup vs baseline: 1.0218x; 1.0218x over previous
//
#include <hip/hip_runtime.h>

#define LSTR 264  // 256 + 8 shorts pad: 528B rows keep 16B alignment for ds_read_b128

typedef short short4v __attribute__((ext_vector_type(4)));
typedef short short8v __attribute__((ext_vector_type(8)));
typedef float f32x4 __attribute__((ext_vector_type(4)));

#define MFMA(a, b, c) __builtin_amdgcn_mfma_f32_16x16x32_bf16((a), (b), (c), 0, 0, 0)

__device__ __forceinline__ short f2bf(float f) {
  unsigned u = __float_as_uint(f);
  unsigned r = u + 0x7fffu + ((u >> 16) & 1u);  // round-to-nearest-even
  return (short)(r >> 16);
}

__device__ __forceinline__ short4v f2bf4(float4 v) {
  short4v s;
  s.x = f2bf(v.x); s.y = f2bf(v.y); s.z = f2bf(v.z); s.w = f2bf(v.w);
  return s;
}

// Packed-fragment index: matrix row n = h*64 + nt*16 + col, k = ks*32 + quad*8 + j
// -> packed[h*16384 + (ks*4+nt)*512 + (quad*16+col)*8 + j]
// A wave's B-fragment load is then ONE contiguous 1KB global_load_dwordx4.

// prep1: wvo = Wo @ Wv (written directly in packed bf16), bvo = Wo@bv + bo
__global__ __launch_bounds__(256) void prep1_kernel(
    const float* __restrict__ Wv, const float* __restrict__ Wo,
    const float* __restrict__ bv, const float* __restrict__ bo,
    short* __restrict__ pvo, float* __restrict__ bvo) {
  __shared__ float srow[256];
  __shared__ float red[256];
  const int n = blockIdx.x, k = threadIdx.x;
  const float wov = Wo[n * 256 + k];
  srow[k] = wov;
  red[k] = wov * bv[k];
  __syncthreads();
  float acc = 0.f;
#pragma unroll 16
  for (int j = 0; j < 256; ++j) acc += srow[j] * Wv[j * 256 + k];
  // packed store of wvo[n][k]
  const int h = n >> 6, nt = (n >> 4) & 3, col = n & 15;
  const int ks = k >> 5, quad = (k >> 3) & 3, j8 = k & 7;
  pvo[h * 16384 + (ks * 4 + nt) * 512 + (quad * 16 + col) * 8 + j8] = f2bf(acc);
  for (int s = 128; s > 0; s >>= 1) {
    if (k < s) red[k] += red[k + s];
    __syncthreads();
  }
  if (k == 0) bvo[n] = red[0] + bo[n];
}

// prep2: pack Wq/Wk/Wv/Wo into fragment order (bf16). 8192 threads, 16B per store.
__global__ __launch_bounds__(256) void pack_kernel(
    const float* __restrict__ Wq, const float* __restrict__ Wk,
    const float* __restrict__ Wv, const float* __restrict__ Wo,
    short* __restrict__ pq, short* __restrict__ pk,
    short* __restrict__ pv, short* __restrict__ po) {
  const int g = blockIdx.x * 256 + threadIdx.x;  // 0..8191
  const int n = g >> 5;
  const int c8 = g & 31;
  const int h = n >> 6, nt = (n >> 4) & 3, col = n & 15;
  const int ks = c8 >> 2, quad = c8 & 3;
  const int src = n * 256 + c8 * 8;
  const int dst = h * 16384 + (ks * 4 + nt) * 512 + (quad * 16 + col) * 8;
  const float4* q4 = (const float4*)(Wq + src);
  const float4* k4 = (const float4*)(Wk + src);
  const float4* v4 = (const float4*)(Wv + src);
  const float4* o4 = (const float4*)(Wo + src);
  float4 qa = q4[0], qb = q4[1], ka = k4[0], kb = k4[1];
  float4 va = v4[0], vb = v4[1], oa = o4[0], ob = o4[1];
  *(short4v*)(pq + dst) = f2bf4(qa); *(short4v*)(pq + dst + 4) = f2bf4(qb);
  *(short4v*)(pk + dst) = f2bf4(ka); *(short4v*)(pk + dst + 4) = f2bf4(kb);
  *(short4v*)(pv + dst) = f2bf4(va); *(short4v*)(pv + dst + 4) = f2bf4(vb);
  *(short4v*)(po + dst) = f2bf4(oa); *(short4v*)(po + dst + 4) = f2bf4(ob);
}

// Merged Q+K pass: two A tiles (p, d), two independent B streams (pq, pk),
// two accumulator sets. Doubles VMEM concurrency vs two sequential passes;
// B prefetch depth-3 per stream (~6 loads in flight).
__device__ __forceinline__ void gemm_qk(const short* Ap, const short* Ad,
                                        const short* __restrict__ wq,
                                        const short* __restrict__ wk,
                                        int col, int quad,
                                        f32x4 accQ[2][4], f32x4 accK[2][4]) {
  const short* p0 = Ap + col * LSTR + quad * 8;
  const short* p1 = p0 + 16 * LSTR;
  const short* d0 = Ad + col * LSTR + quad * 8;
  const short* d1 = d0 + 16 * LSTR;
  short8v ap0 = *(const short8v*)p0;
  short8v ap1 = *(const short8v*)p1;
  short8v ad0 = *(const short8v*)d0;
  short8v ad1 = *(const short8v*)d1;
  short8v qb0 = *(const short8v*)(wq);
  short8v qb1 = *(const short8v*)(wq + 512);
  short8v qb2 = *(const short8v*)(wq + 1024);
  short8v kb0 = *(const short8v*)(wk);
  short8v kb1 = *(const short8v*)(wk + 512);
  short8v kb2 = *(const short8v*)(wk + 1024);
#pragma unroll
  for (int ks = 0; ks < 8; ++ks) {
    const int kn = (ks + 1) & 7;  // wrap avoids OOB; tail reloads are free
    short8v ap0n = *(const short8v*)(p0 + kn * 32);
    short8v ap1n = *(const short8v*)(p1 + kn * 32);
    short8v ad0n = *(const short8v*)(d0 + kn * 32);
    short8v ad1n = *(const short8v*)(d1 + kn * 32);
#pragma unroll
    for (int nt = 0; nt < 4; ++nt) {
      const int f = ks * 4 + nt;
      short8v qbn = *(const short8v*)(wq + ((f + 3) & 31) * 512);
      short8v kbn = *(const short8v*)(wk + ((f + 3) & 31) * 512);
      accQ[0][nt] = MFMA(ap0, qb0, accQ[0][nt]);
      accQ[1][nt] = MFMA(ap1, qb0, accQ[1][nt]);
      accK[0][nt] = MFMA(ad0, kb0, accK[0][nt]);
      accK[1][nt] = MFMA(ad1, kb0, accK[1][nt]);
      qb0 = qb1; qb1 = qb2; qb2 = qbn;
      kb0 = kb1; kb1 = kb2; kb2 = kbn;
    }
    ap0 = ap0n; ap1 = ap1n; ad0 = ad0n; ad1 = ad1n;
  }
}

// Single-A pass (V): B prefetch deepened to depth-4.
__device__ __forceinline__ void gemm_v(const short* A, const short* __restrict__ wb,
                                       int col, int quad, f32x4 acc[2][4]) {
  const short* a0p = A + col * LSTR + quad * 8;
  const short* a1p = a0p + 16 * LSTR;
  short8v a0c = *(const short8v*)a0p;
  short8v a1c = *(const short8v*)a1p;
  short8v b0 = *(const short8v*)(wb);
  short8v b1 = *(const short8v*)(wb + 512);
  short8v b2 = *(const short8v*)(wb + 1024);
  short8v b3 = *(const short8v*)(wb + 1536);
#pragma unroll
  for (int ks = 0; ks < 8; ++ks) {
    const int kn = (ks + 1) & 7;
    short8v a0n = *(const short8v*)(a0p + kn * 32);
    short8v a1n = *(const short8v*)(a1p + kn * 32);
#pragma unroll
    for (int nt = 0; nt < 4; ++nt) {
      const int f = ks * 4 + nt;
      short8v bn = *(const short8v*)(wb + ((f + 4) & 31) * 512);
      acc[0][nt] = MFMA(a0c, b0, acc[0][nt]);
      acc[1][nt] = MFMA(a1c, b0, acc[1][nt]);
      b0 = b1; b1 = b2; b2 = b3; b3 = bn;
    }
    a0c = a0n; a1c = a1n;
  }
}

// Merged O pass: two A tiles (c1, gdV), two B streams (pvo, po), two acc sets
// (summed in epilogue to avoid dependent back-to-back MFMAs on one acc).
__device__ __forceinline__ void gemm_o(const short* Ac, const short* Ag,
                                       const short* __restrict__ wvo,
                                       const short* __restrict__ wo,
                                       int col, int quad,
                                       f32x4 accA[2][4], f32x4 accB[2][4]) {
  const short* c0p = Ac + col * LSTR + quad * 8;
  const short* c1p = c0p + 16 * LSTR;
  const short* g0p = Ag + col * LSTR + quad * 8;
  const short* g1p = g0p + 16 * LSTR;
  short8v ac0 = *(const short8v*)c0p;
  short8v ac1 = *(const short8v*)c1p;
  short8v ag0 = *(const short8v*)g0p;
  short8v ag1 = *(const short8v*)g1p;
  short8v vb0 = *(const short8v*)(wvo);
  short8v vb1 = *(const short8v*)(wvo + 512);
  short8v vb2 = *(const short8v*)(wvo + 1024);
  short8v ob0 = *(const short8v*)(wo);
  short8v ob1 = *(const short8v*)(wo + 512);
  short8v ob2 = *(const short8v*)(wo + 1024);
#pragma unroll
  for (int ks = 0; ks < 8; ++ks) {
    const int kn = (ks + 1) & 7;
    short8v ac0n = *(const short8v*)(c0p + kn * 32);
    short8v ac1n = *(const short8v*)(c1p + kn * 32);
    short8v ag0n = *(const short8v*)(g0p + kn * 32);
    short8v ag1n = *(const short8v*)(g1p + kn * 32);
#pragma unroll
    for (int nt = 0; nt < 4; ++nt) {
      const int f = ks * 4 + nt;
      short8v vbn = *(const short8v*)(wvo + ((f + 3) & 31) * 512);
      short8v obn = *(const short8v*)(wo + ((f + 3) & 31) * 512);
      accA[0][nt] = MFMA(ac0, vb0, accA[0][nt]);
      accA[1][nt] = MFMA(ac1, vb0, accA[1][nt]);
      accB[0][nt] = MFMA(ag0, ob0, accB[0][nt]);
      accB[1][nt] = MFMA(ag1, ob0, accB[1][nt]);
      vb0 = vb1; vb1 = vb2; vb2 = vbn;
      ob0 = ob1; ob1 = ob2; ob2 = obn;
    }
    ac0 = ac0n; ac1 = ac1n; ag0 = ag0n; ag1 = ag1n;
  }
}

__global__ __launch_bounds__(256, 3) void fused_kernel(
    const float* __restrict__ pred, const float* __restrict__ cemb,
    const short* __restrict__ pq, const short* __restrict__ pk,
    const short* __restrict__ pv, const short* __restrict__ po,
    const short* __restrict__ pvo, const float* __restrict__ bq,
    const float* __restrict__ bvo, float* __restrict__ out) {
  __shared__ __align__(16) short bufP[32 * LSTR];   // p tile, later gdV tile
  __shared__ __align__(16) short bufD[32 * LSTR];   // c0-c1 tile
  __shared__ __align__(16) short bufC1[32 * LSTR];  // c1 tile
  const int tid = threadIdx.x;
  const size_t t0 = (size_t)blockIdx.x * 32;

  // Stage: all 24 float4 HBM loads per thread issued up-front into registers,
  // then convert fp32->bf16 and write LDS.
  {
    const int r = tid >> 3;
    const int c0 = tid & 7;
    const float4* prow = (const float4*)(pred + (t0 + r) * 256);
    const float4* crow = (const float4*)(cemb + (t0 + r) * 512);
    float4 pv_[8], av[8], bw[8];
#pragma unroll
    for (int i = 0; i < 8; ++i) pv_[i] = prow[c0 + 8 * i];
#pragma unroll
    for (int i = 0; i < 8; ++i) av[i] = crow[c0 + 8 * i];
#pragma unroll
    for (int i = 0; i < 8; ++i) bw[i] = crow[64 + c0 + 8 * i];
    short* pd = bufP + r * LSTR;
    short* dd = bufD + r * LSTR;
    short* cd = bufC1 + r * LSTR;
#pragma unroll
    for (int i = 0; i < 8; ++i) {
      const int j = c0 + 8 * i;
      *(short4v*)(pd + 4 * j) = f2bf4(pv_[i]);
      float4 d4 = make_float4(av[i].x - bw[i].x, av[i].y - bw[i].y,
                              av[i].z - bw[i].z, av[i].w - bw[i].w);
      *(short4v*)(dd + 4 * j) = f2bf4(d4);
      *(short4v*)(cd + 4 * j) = f2bf4(bw[i]);
    }
  }
  __syncthreads();

  const int lane = tid & 63;
  const int w = tid >> 6;      // wave = head
  const int col = lane & 15;
  const int quad = lane >> 4;
  const int nbase = w * 64;
  const int woff = w * 16384 + lane * 8;  // packed-weight base for this wave

  float bqv[4];
#pragma unroll
  for (int nt = 0; nt < 4; ++nt) bqv[nt] = bq[nbase + nt * 16 + col];

  // Pass 1: Q and dK GEMMs, merged (dual VMEM streams).
  f32x4 accQ[2][4] = {};
  f32x4 accK[2][4] = {};
  gemm_qk(bufP, bufD, pq + woff, pk + woff, col, quad, accQ, accK);

  // z[m][head] = (Q+bq) . dK over this head's 64 cols; reduce across the
  // 16 lanes of each quad-row; g = sigmoid(z/sqrt(D))
  float g[2][4];
#pragma unroll
  for (int ms = 0; ms < 2; ++ms) {
#pragma unroll
    for (int r = 0; r < 4; ++r) {
      float zz = 0.f;
#pragma unroll
      for (int nt = 0; nt < 4; ++nt)
        zz += (accQ[ms][nt][r] + bqv[nt]) * accK[ms][nt][r];
      zz += __shfl_xor(zz, 1);
      zz += __shfl_xor(zz, 2);
      zz += __shfl_xor(zz, 4);
      zz += __shfl_xor(zz, 8);
      g[ms][r] = 1.f / (1.f + __expf(-0.125f * zz));
    }
  }

  // Pass 2: dV GEMM.
  f32x4 accV[2][4] = {};
  gemm_v(bufD, pv + woff, col, quad, accV);

  __syncthreads();  // all waves done reading bufP (Q gemm)
  // gdV -> bufP as bf16 A-tile (C/D layout: row = quad*4+reg, col = nt*16+col)
#pragma unroll
  for (int ms = 0; ms < 2; ++ms)
#pragma unroll
    for (int nt = 0; nt < 4; ++nt)
#pragma unroll
      for (int r = 0; r < 4; ++r)
        bufP[(ms * 16 + quad * 4 + r) * LSTR + nbase + nt * 16 + col] =
            f2bf(g[ms][r] * accV[ms][nt][r]);
  __syncthreads();

  float bov[4];
#pragma unroll
  for (int nt = 0; nt < 4; ++nt) bov[nt] = bvo[nbase + nt * 16 + col];

  // Pass 3: out = c1 @ Wvo^T + gdV @ Wo^T + bvo, merged (dual A, dual B).
  f32x4 accO1[2][4] = {};
  f32x4 accO2[2][4] = {};
  gemm_o(bufC1, bufP, pvo + woff, po + woff, col, quad, accO1, accO2);

#pragma unroll
  for (int ms = 0; ms < 2; ++ms)
#pragma unroll
    for (int nt = 0; nt < 4; ++nt)
#pragma unroll
      for (int r = 0; r < 4; ++r)
        out[(t0 + ms * 16 + quad * 4 + r) * 256 + nbase + nt * 16 + col] =
            accO1[ms][nt][r] + accO2[ms][nt][r] + bov[nt];
}

extern "C" void kernel_launch(void* const* d_in, const int* in_sizes, int n_in,
                              void* d_out, int out_size, void* d_ws, size_t ws_size,
                              hipStream_t stream) {
  const float* pred = (const float*)d_in[0];
  const float* cemb = (const float*)d_in[1];
  const float* Wq = (const float*)d_in[2];
  const float* bq = (const float*)d_in[3];
  const float* Wk = (const float*)d_in[4];
  const float* Wv = (const float*)d_in[6];
  const float* bv = (const float*)d_in[7];
  const float* Wo = (const float*)d_in[8];
  const float* bo = (const float*)d_in[9];
  float* out = (float*)d_out;

  short* pq = (short*)d_ws;
  short* pk = pq + 65536;
  short* pv = pk + 65536;
  short* po = pv + 65536;
  short* pvo = po + 65536;
  float* bvo = (float*)(pvo + 65536);  // total ws use: 656,384 bytes

  prep1_kernel<<<256, 256, 0, stream>>>(Wv, Wo, bv, bo, pvo, bvo);
  pack_kernel<<<32, 256, 0, stream>>>(Wq, Wk, Wv, Wo, pq, pk, pv, po);
  fused_kernel<<<2048, 256, 0, stream>>>(pred, cemb, pq, pk, pv, po, pvo, bq, bvo, out);
}